// Round 1
// baseline (916.327 us; speedup 1.0000x reference)
//
#include <hip/hip_runtime.h>

// ---------------------------------------------------------------------------
// QuantumImageEncoder R12: attack the two measured non-issue bottlenecks.
//  1) fc1 read the 200KB wT2 TWICE per block (wave=(sample,half)) -> 1.6GB of
//     L2 traffic/dispatch, saturating the per-CU L2 port. Waves now each own
//     a disjoint g-quarter for BOTH samples: one weight load feeds 2 FMA
//     chains -> 200KB/block (halved).
//  2) LDS 31.7KB capped occupancy at 5 blocks/CU. Conv weights move out of
//     LDS to per-lane global loads (L1-broadcast; conv2 repacked float4-
//     aligned [ci][c2][12] in prep, double-buffered one ci ahead).
//     LDS -> ~26.4KB -> 6 blocks/CU (24 waves).
//  Also: quantum kernel 4 lanes/sample (grid B/32=256 blocks, was 64) and
//  fc1 gets 4 independent accumulator chains for deeper L2-load pipelining.
// ---------------------------------------------------------------------------

#define B_EPS 1e-5f

// ---------------- prep: U build + stats zero + conv2-weight repack (block 0),
// ----------------       fc1_w -> wT2[k4][64][4] (blocks 1..196) -------------
__global__ void prep_kernel(const float* __restrict__ rl,
                            const float* __restrict__ f1w,
                            const float* __restrict__ c2w,
                            float* __restrict__ Uout,
                            float* __restrict__ wT2,
                            float* __restrict__ w2q,
                            float* __restrict__ stats)
{
    if (blockIdx.x == 0) {
        __shared__ float2 U[16][16];
        int t = threadIdx.x;                 // 256 threads
        int r = t >> 4, cc = t & 15;
        U[r][cc] = (r == cc) ? make_float2(1.f, 0.f) : make_float2(0.f, 0.f);
        stats[t] = 0.f;                      // 512-float sharded stats
        stats[t + 256] = 0.f;
        // conv2 weights -> w2q[(ci*16+c2)*12 + q], q<9 valid, float4-aligned
        for (int i = t; i < 16 * 8 * 12; i += 256) {
            int ci = i / 192, rem = i - ci * 192;
            int c2 = rem / 12, qq = rem - c2 * 12;
            w2q[i] = (qq < 9) ? c2w[c2 * 72 + ci * 9 + qq] : 0.f;
        }
        __syncthreads();
        for (int op = 0; op < 30; op++) {
            int kind = op & 3;               // 0=rx,1=ry,2=rz,3=cnot ; wire = op%4
            float2 cur = U[r][cc];
            float2 nv;
            if (kind == 3) {
                float2 part = U[r ^ 8][cc];  // control wire3 (bit 1), target wire0 (bit 8)
                nv = (r & 1) ? part : cur;
            } else {
                int m = 8 >> kind;           // wire w=kind -> bit (3-w)
                float theta = rl[op - (op >> 2)];
                float ch = cosf(0.5f * theta), sh = sinf(0.5f * theta);
                float2 part = U[r ^ m][cc];
                int br = (r & m) ? 1 : 0;
                float2 gc, gp;
                if (kind == 0)      { gc = make_float2(ch, 0.f);           gp = make_float2(0.f, -sh); }
                else if (kind == 1) { gc = make_float2(ch, 0.f);           gp = make_float2(br ? sh : -sh, 0.f); }
                else                { gc = make_float2(ch, br ? sh : -sh); gp = make_float2(0.f, 0.f); }
                nv.x = gc.x*cur.x - gc.y*cur.y + gp.x*part.x - gp.y*part.y;
                nv.y = gc.x*cur.y + gc.y*cur.x + gp.x*part.y + gp.y*part.x;
            }
            __syncthreads();
            U[r][cc] = nv;
            __syncthreads();
        }
        ((float2*)Uout)[t] = U[r][cc];
    } else {
        int id = (blockIdx.x - 1) * 256 + threadIdx.x;
        if (id < 784 * 64) {
            int k = id >> 6, o = id & 63;
            // wT2 float index = (k4*64 + o)*4 + (k&3)
            wT2[(((k >> 2) * 64 + o) << 2) + (k & 3)] = f1w[o * 784 + k];
        }
    }
}

// ---------------- conv backbone + fused fc: 2 samples / block, 4 waves ------
__global__ __launch_bounds__(256, 6) void conv_kernel(
    const float* __restrict__ x,  const float* __restrict__ c1w,
    const float* __restrict__ c1b, const float* __restrict__ w2q,
    const float* __restrict__ c2b, const float* __restrict__ wT2,
    const float* __restrict__ f1b, const float* __restrict__ f2w,
    const float* __restrict__ f2bias, float* __restrict__ feat,
    float* __restrict__ stats)
{
    __shared__ union alignas(16) {
        float xin[2][30 * 32];     // padded 28x28, row stride 32, halo ring
        float flat[2][800];        // reused after conv1 (conv2 pooled output)
    } u;
    __shared__ union alignas(16) {
        float p1[2][8 * 292];      // [ch][row16][col18]+pad, stride 292
        struct { float part[2][4][64]; float hs[2][64]; } fc;  // p1 dead after P3
    } pu;

    int t = threadIdx.x;
    int w = t >> 6, lane = t & 63;

    // conv1 weights for this lane: per-lane global loads (8 lanes share an
    // address -> L1 broadcast). Issued before staging so latency is covered.
    int c1 = lane >> 3;
    float wk1[9];
    #pragma unroll
    for (int q = 0; q < 9; q++) wk1[q] = c1w[c1 * 9 + q];
    float bias1 = c1b[c1];

    // ---- P1: zero xin + p1 (halo correctness)
    {
        float4 z = make_float4(0.f, 0.f, 0.f, 0.f);
        float4* xz = (float4*)u.xin;
        for (int i = t; i < 2 * 30 * 32 / 4; i += 256) xz[i] = z;
        float4* pz = (float4*)pu.p1;
        for (int i = t; i < 2 * 8 * 292 / 4; i += 256) pz[i] = z;
    }
    __syncthreads();

    // ---- stage input (2 samples), shifted +1 for the zero halo
    {
        const float4* xg = (const float4*)(x + (size_t)blockIdx.x * 2 * 784);
        for (int i = t; i < 392; i += 256) {
            float4 v = xg[i];
            int s = i / 196, q = (i - s * 196) * 4;
            float vv[4] = {v.x, v.y, v.z, v.w};
            #pragma unroll
            for (int j = 0; j < 4; j++) {
                int p = q + j, rr = p / 28, cc = p - rr * 28;
                u.xin[s][(rr + 1) * 32 + cc + 1] = vv[j];
            }
        }
    }
    __syncthreads();

    // ---- P2: conv1 + relu + pool -> p1   (wave=(s,h), lane=(ch,colgroup))
    {
        int s = w >> 1, h = w & 1;
        int g = lane & 7;
        if (g < 7) {
            const float* xb = &u.xin[s][4 * g];
            float* pout = &pu.p1[s][c1 * 292];
            for (int ii = 0; ii < 7; ii++) {
                int i = h * 7 + ii;                     // pooled row 0..13
                const float* r = xb + 2 * i * 32;
                float rv[4][6];
                #pragma unroll
                for (int dr = 0; dr < 4; dr++) {
                    float2 a = *(const float2*)(r + dr * 32);
                    float2 b = *(const float2*)(r + dr * 32 + 2);
                    float2 c2v = *(const float2*)(r + dr * 32 + 4);
                    rv[dr][0] = a.x;  rv[dr][1] = a.y;
                    rv[dr][2] = b.x;  rv[dr][3] = b.y;
                    rv[dr][4] = c2v.x; rv[dr][5] = c2v.y;
                }
                float o[2][4];
                #pragma unroll
                for (int dr = 0; dr < 2; dr++)
                    #pragma unroll
                    for (int j = 0; j < 4; j++) {
                        float acc = bias1;
                        #pragma unroll
                        for (int ky = 0; ky < 3; ky++)
                            #pragma unroll
                            for (int kx = 0; kx < 3; kx++)
                                acc = fmaf(wk1[ky * 3 + kx], rv[dr + ky][j + kx], acc);
                        o[dr][j] = acc;
                    }
                #pragma unroll
                for (int jj = 0; jj < 2; jj++) {
                    float m = fmaxf(fmaxf(o[0][2 * jj], o[0][2 * jj + 1]),
                                    fmaxf(o[1][2 * jj], o[1][2 * jj + 1]));
                    pout[(i + 1) * 18 + 1 + 2 * g + jj] = fmaxf(m, 0.f);
                }
            }
        }
    }
    __syncthreads();

    // ---- P3: conv2 + relu + pool -> u.flat (xin dead now)
    // weights from global w2q[(ci*16+c2)*12] (L1-resident, 48B/lane/ci),
    // double-buffered one ci ahead so L1 latency hides under the 72 FMAs.
    {
        int s = w >> 1, h = w & 1;
        int c2 = lane >> 2, g2 = lane & 3;
        int i0 = h * 4;                                 // h=0: i 0..3, h=1: i 4..6
        float bias = c2b[c2];
        const float4* wqb = (const float4*)w2q + c2 * 3;  // + ci*48 per channel
        float4 wa = wqb[0], wb = wqb[1], wc = wqb[2];
        float acc[4][2][4];
        #pragma unroll
        for (int ii = 0; ii < 4; ii++)
            #pragma unroll
            for (int dr = 0; dr < 2; dr++)
                #pragma unroll
                for (int j = 0; j < 4; j++) acc[ii][dr][j] = bias;

        const float* pbase = &pu.p1[s][4 * g2] + i0 * 2 * 18;
        for (int ci = 0; ci < 8; ci++) {
            float wk[9] = {wa.x, wa.y, wa.z, wa.w, wb.x, wb.y, wb.z, wb.w, wc.x};
            if (ci < 7) {                               // prefetch next ci
                wa = wqb[(ci + 1) * 48];
                wb = wqb[(ci + 1) * 48 + 1];
                wc = wqb[(ci + 1) * 48 + 2];
            }
            const float* pc_ = pbase + ci * 292;
            #pragma unroll
            for (int ii = 0; ii < 4; ii++) {
                if (ii < 3 || h == 0) {
                    float rv[4][6];
                    #pragma unroll
                    for (int dr = 0; dr < 4; dr++) {
                        const float* rp = pc_ + (ii * 2 + dr) * 18;
                        float2 a = *(const float2*)rp;
                        float2 b = *(const float2*)(rp + 2);
                        float2 cc = *(const float2*)(rp + 4);
                        rv[dr][0] = a.x;  rv[dr][1] = a.y;
                        rv[dr][2] = b.x;  rv[dr][3] = b.y;
                        rv[dr][4] = cc.x; rv[dr][5] = cc.y;
                    }
                    #pragma unroll
                    for (int dr = 0; dr < 2; dr++)
                        #pragma unroll
                        for (int j = 0; j < 4; j++) {
                            float a2 = acc[ii][dr][j];
                            #pragma unroll
                            for (int ky = 0; ky < 3; ky++)
                                #pragma unroll
                                for (int kx = 0; kx < 3; kx++)
                                    a2 = fmaf(wk[ky * 3 + kx], rv[dr + ky][j + kx], a2);
                            acc[ii][dr][j] = a2;
                        }
                }
            }
        }
        #pragma unroll
        for (int ii = 0; ii < 4; ii++) {
            if (ii < 3 || h == 0) {
                int i = i0 + ii;
                #pragma unroll
                for (int jj = 0; jj < 2; jj++) {
                    int pc = 2 * g2 + jj;
                    if (pc < 7) {
                        float m = fmaxf(fmaxf(acc[ii][0][2 * jj], acc[ii][0][2 * jj + 1]),
                                        fmaxf(acc[ii][1][2 * jj], acc[ii][1][2 * jj + 1]));
                        u.flat[s][c2 * 49 + i * 7 + pc] = fmaxf(m, 0.f);
                    }
                }
            }
        }
    }
    __syncthreads();   // p1 dead from here; pu.fc live

    // ---- P5: fc1 partials. Each wave owns g-quarter [w*49, w*49+49) for
    // BOTH samples: one weight float4 feeds 2 FMA chains -> halved L2
    // traffic (200KB/block). 4 independent chains deepen in-flight loads.
    {
        const float* fl0 = u.flat[0];
        const float* fl1 = u.flat[1];
        const float4* wp4 = (const float4*)wT2 + lane;   // + g*64 per k4-group
        int g0 = w * 49;
        float a00 = 0.f, a01 = 0.f, a10 = 0.f, a11 = 0.f;
        #pragma unroll 2
        for (int g = g0; g < g0 + 48; g += 2) {
            float4 wv0 = wp4[(size_t)g * 64];
            float4 wv1 = wp4[(size_t)(g + 1) * 64];
            float4 f00 = *(const float4*)&fl0[4 * g];
            float4 f10 = *(const float4*)&fl1[4 * g];
            float4 f01 = *(const float4*)&fl0[4 * g + 4];
            float4 f11 = *(const float4*)&fl1[4 * g + 4];
            a00 = fmaf(f00.x, wv0.x, fmaf(f00.y, wv0.y, fmaf(f00.z, wv0.z, fmaf(f00.w, wv0.w, a00))));
            a10 = fmaf(f10.x, wv0.x, fmaf(f10.y, wv0.y, fmaf(f10.z, wv0.z, fmaf(f10.w, wv0.w, a10))));
            a01 = fmaf(f01.x, wv1.x, fmaf(f01.y, wv1.y, fmaf(f01.z, wv1.z, fmaf(f01.w, wv1.w, a01))));
            a11 = fmaf(f11.x, wv1.x, fmaf(f11.y, wv1.y, fmaf(f11.z, wv1.z, fmaf(f11.w, wv1.w, a11))));
        }
        {   // tail g0+48 (49 groups per quarter)
            int g = g0 + 48;
            float4 wv = wp4[(size_t)g * 64];
            float4 f0 = *(const float4*)&fl0[4 * g];
            float4 f1 = *(const float4*)&fl1[4 * g];
            a00 = fmaf(f0.x, wv.x, fmaf(f0.y, wv.y, fmaf(f0.z, wv.z, fmaf(f0.w, wv.w, a00))));
            a10 = fmaf(f1.x, wv.x, fmaf(f1.y, wv.y, fmaf(f1.z, wv.z, fmaf(f1.w, wv.w, a10))));
        }
        pu.fc.part[0][w][lane] = a00 + a01;
        pu.fc.part[1][w][lane] = a10 + a11;
    }
    __syncthreads();

    // ---- P6: combine quarters + bias + relu
    if (t < 128) {
        int s2 = t >> 6, o = t & 63;
        float h = pu.fc.part[s2][0][o] + pu.fc.part[s2][1][o]
                + pu.fc.part[s2][2][o] + pu.fc.part[s2][3][o] + f1b[o];
        pu.fc.hs[s2][o] = fmaxf(h, 0.f);
    }
    __syncthreads();

    // ---- P7: fc2 + feat + sharded BN stats
    if (t < 8) {
        int s = t >> 2, j = t & 3;
        float a = f2bias[j];
        #pragma unroll
        for (int o = 0; o < 64; o++) a = fmaf(pu.fc.hs[s][o], f2w[j * 64 + o], a);
        feat[((size_t)blockIdx.x * 2 + s) * 4 + j] = a;
        int g = blockIdx.x & 63;
        atomicAdd(&stats[g * 8 + j], a);
        atomicAdd(&stats[g * 8 + 4 + j], a * a);
    }
}

// ---------------- BN + encoder + U matvec + PauliZ measure ------------------
// 4 lanes per sample (each does 4 rows of the 16x16 matvec, shfl-reduce),
// grid = B/32 blocks -> 256 blocks (was 64: only 1/4 of the CUs active).
__global__ __launch_bounds__(128) void quantum_kernel(
    const float* __restrict__ feat, const float* __restrict__ Ug,
    const float* __restrict__ stats, const float* __restrict__ bn_g,
    const float* __restrict__ bn_b, float* __restrict__ out, int B)
{
    __shared__ float2 Us[256];
    __shared__ float sm[8];
    int t = threadIdx.x;                  // 128 threads
    for (int i = t; i < 256; i += 128) Us[i] = ((const float2*)Ug)[i];
    if (t < 8) sm[t] = 0.f;
    __syncthreads();
    {   // parallel gather of 64 shards x 8 (index mod 8 preserved by +128)
        float v = stats[t] + stats[t + 128] + stats[t + 256] + stats[t + 384];
        atomicAdd(&sm[t & 7], v);
    }
    __syncthreads();
    int q = t & 3;                        // row-quad within the sample
    int s = blockIdx.x * 32 + (t >> 2);
    float4 fv = ((const float4*)feat)[s];
    float f[4] = {fv.x, fv.y, fv.z, fv.w};
    float cn[4], sn[4];
    float invB = 1.0f / (float)B;
    #pragma unroll
    for (int w = 0; w < 4; w++) {
        float mean = sm[w] * invB;
        float var  = sm[4 + w] * invB - mean * mean;
        float fh = (f[w] - mean) / sqrtf(var + B_EPS) * bn_g[w] + bn_b[w];
        cn[w] = cosf(0.5f * fh);
        sn[w] = sinf(0.5f * fh);
    }
    // encoded product state: s0_k = prod(c/s) * (-i)^popcount(k)
    float re0[16], im0[16];
    #pragma unroll
    for (int k = 0; k < 16; k++) {
        float mag = ((k & 8) ? sn[0] : cn[0]) * ((k & 4) ? sn[1] : cn[1]) *
                    ((k & 2) ? sn[2] : cn[2]) * ((k & 1) ? sn[3] : cn[3]);
        int m = __popc(k) & 3;
        re0[k] = (m == 0) ? mag : (m == 2) ? -mag : 0.f;
        im0[k] = (m == 1) ? -mag : (m == 3) ? mag : 0.f;
    }
    float o0 = 0.f, o1 = 0.f, o2 = 0.f, o3 = 0.f;
    #pragma unroll
    for (int i = 0; i < 4; i++) {
        int r = q * 4 + i;
        float ar = 0.f, ai = 0.f;
        #pragma unroll
        for (int k = 0; k < 16; k++) {
            float2 uu = Us[r * 16 + k];
            ar += uu.x * re0[k] - uu.y * im0[k];
            ai += uu.x * im0[k] + uu.y * re0[k];
        }
        float p = ar * ar + ai * ai;
        o0 += (r & 8) ? -p : p;
        o1 += (r & 4) ? -p : p;
        o2 += (r & 2) ? -p : p;
        o3 += (r & 1) ? -p : p;
    }
    // reduce across the 4-lane group
    o0 += __shfl_xor(o0, 1);  o0 += __shfl_xor(o0, 2);
    o1 += __shfl_xor(o1, 1);  o1 += __shfl_xor(o1, 2);
    o2 += __shfl_xor(o2, 1);  o2 += __shfl_xor(o2, 2);
    o3 += __shfl_xor(o3, 1);  o3 += __shfl_xor(o3, 2);
    if (q == 0) {
        float4 ov = {o0, o1, o2, o3};
        ((float4*)out)[s] = ov;
    }
}

// ---------------------------------------------------------------------------
extern "C" void kernel_launch(void* const* d_in, const int* in_sizes, int n_in,
                              void* d_out, int out_size, void* d_ws, size_t ws_size,
                              hipStream_t stream)
{
    const float* x   = (const float*)d_in[0];
    const float* c1w = (const float*)d_in[1];
    const float* c1b = (const float*)d_in[2];
    const float* c2w = (const float*)d_in[3];
    const float* c2b = (const float*)d_in[4];
    const float* f1w = (const float*)d_in[5];
    const float* f1b = (const float*)d_in[6];
    const float* f2w = (const float*)d_in[7];
    const float* f2b = (const float*)d_in[8];
    const float* bng = (const float*)d_in[9];
    const float* bnb = (const float*)d_in[10];
    const float* rl  = (const float*)d_in[11];
    float* out = (float*)d_out;

    int B = in_sizes[0] / 784;

    float* wsf   = (float*)d_ws;
    float* feat  = wsf;                          // B*4
    float* wT2   = feat + (size_t)B * 4;         // 784*64 (as [k4][64][4])
    float* U     = wT2 + 784 * 64;               // 512 (float2[256])
    float* stats = U + 512;                      // 512 (64 shards x 8)
    float* w2q   = stats + 512;                  // 1536 ([ci][c2][12], q<9 used)

    prep_kernel<<<197, 256, 0, stream>>>(rl, f1w, c2w, U, wT2, w2q, stats);
    conv_kernel<<<B / 2, 256, 0, stream>>>(x, c1w, c1b, w2q, c2b, wT2,
                                           f1b, f2w, f2b, feat, stats);
    quantum_kernel<<<B / 32, 128, 0, stream>>>(feat, U, stats, bng, bnb, out, B);
}

// Round 2
// 202.054 us; speedup vs baseline: 4.5351x; 4.5351x over previous
//
#include <hip/hip_runtime.h>

// ---------------------------------------------------------------------------
// QuantumImageEncoder R13: R12 minus the spill bomb.
//  R12 post-mortem: __launch_bounds__(256,6) forced a ~40-VGPR budget ->
//  ~3.7KB/thread scratch spill -> 3.9GB HBM traffic/dispatch -> 851us.
//  R13 reverts to __launch_bounds__(256) (R11's 76-VGPR regime) and keeps
//  the two structural R12 changes, which were never actually measured:
//   1) fc1 reads the 200KB wT2 ONCE per block (wave owns a g-quarter for
//      both samples) -> halved L2 traffic vs R11.
//   2) conv weights out of LDS (global, L1-broadcast; conv2 repacked
//      [ci][c2][12] float4-aligned) -> LDS 26.6KB -> 6 blocks/CU by LDS.
//  Guard: #pragma unroll 1 on the ci loop so the compiler can't hoist all
//  24 weight float4s and recreate the pressure problem.
// ---------------------------------------------------------------------------

#define B_EPS 1e-5f

// ---------------- prep: U build + stats zero + conv2-weight repack (block 0),
// ----------------       fc1_w -> wT2[k4][64][4] (blocks 1..196) -------------
__global__ void prep_kernel(const float* __restrict__ rl,
                            const float* __restrict__ f1w,
                            const float* __restrict__ c2w,
                            float* __restrict__ Uout,
                            float* __restrict__ wT2,
                            float* __restrict__ w2q,
                            float* __restrict__ stats)
{
    if (blockIdx.x == 0) {
        __shared__ float2 U[16][16];
        int t = threadIdx.x;                 // 256 threads
        int r = t >> 4, cc = t & 15;
        U[r][cc] = (r == cc) ? make_float2(1.f, 0.f) : make_float2(0.f, 0.f);
        stats[t] = 0.f;                      // 512-float sharded stats
        stats[t + 256] = 0.f;
        // conv2 weights -> w2q[(ci*16+c2)*12 + q], q<9 valid, float4-aligned
        for (int i = t; i < 16 * 8 * 12; i += 256) {
            int ci = i / 192, rem = i - ci * 192;
            int c2 = rem / 12, qq = rem - c2 * 12;
            w2q[i] = (qq < 9) ? c2w[c2 * 72 + ci * 9 + qq] : 0.f;
        }
        __syncthreads();
        for (int op = 0; op < 30; op++) {
            int kind = op & 3;               // 0=rx,1=ry,2=rz,3=cnot ; wire = op%4
            float2 cur = U[r][cc];
            float2 nv;
            if (kind == 3) {
                float2 part = U[r ^ 8][cc];  // control wire3 (bit 1), target wire0 (bit 8)
                nv = (r & 1) ? part : cur;
            } else {
                int m = 8 >> kind;           // wire w=kind -> bit (3-w)
                float theta = rl[op - (op >> 2)];
                float ch = cosf(0.5f * theta), sh = sinf(0.5f * theta);
                float2 part = U[r ^ m][cc];
                int br = (r & m) ? 1 : 0;
                float2 gc, gp;
                if (kind == 0)      { gc = make_float2(ch, 0.f);           gp = make_float2(0.f, -sh); }
                else if (kind == 1) { gc = make_float2(ch, 0.f);           gp = make_float2(br ? sh : -sh, 0.f); }
                else                { gc = make_float2(ch, br ? sh : -sh); gp = make_float2(0.f, 0.f); }
                nv.x = gc.x*cur.x - gc.y*cur.y + gp.x*part.x - gp.y*part.y;
                nv.y = gc.x*cur.y + gc.y*cur.x + gp.x*part.y + gp.y*part.x;
            }
            __syncthreads();
            U[r][cc] = nv;
            __syncthreads();
        }
        ((float2*)Uout)[t] = U[r][cc];
    } else {
        int id = (blockIdx.x - 1) * 256 + threadIdx.x;
        if (id < 784 * 64) {
            int k = id >> 6, o = id & 63;
            // wT2 float index = (k4*64 + o)*4 + (k&3)
            wT2[(((k >> 2) * 64 + o) << 2) + (k & 3)] = f1w[o * 784 + k];
        }
    }
}

// ---------------- conv backbone + fused fc: 2 samples / block, 4 waves ------
__global__ __launch_bounds__(256) void conv_kernel(
    const float* __restrict__ x,  const float* __restrict__ c1w,
    const float* __restrict__ c1b, const float* __restrict__ w2q,
    const float* __restrict__ c2b, const float* __restrict__ wT2,
    const float* __restrict__ f1b, const float* __restrict__ f2w,
    const float* __restrict__ f2bias, float* __restrict__ feat,
    float* __restrict__ stats)
{
    __shared__ union alignas(16) {
        float xin[2][30 * 32];     // padded 28x28, row stride 32, halo ring
        float flat[2][800];        // reused after conv1 (conv2 pooled output)
    } u;
    __shared__ union alignas(16) {
        float p1[2][8 * 292];      // [ch][row16][col18]+pad, stride 292
        struct { float part[2][4][64]; float hs[2][64]; } fc;  // p1 dead after P3
    } pu;

    int t = threadIdx.x;
    int w = t >> 6, lane = t & 63;

    // conv1 weights for this lane: per-lane global loads (8 lanes share an
    // address -> L1 broadcast). Issued before staging so latency is covered.
    int c1 = lane >> 3;
    float wk1[9];
    #pragma unroll
    for (int q = 0; q < 9; q++) wk1[q] = c1w[c1 * 9 + q];
    float bias1 = c1b[c1];

    // ---- P1: zero xin + p1 (halo correctness)
    {
        float4 z = make_float4(0.f, 0.f, 0.f, 0.f);
        float4* xz = (float4*)u.xin;
        for (int i = t; i < 2 * 30 * 32 / 4; i += 256) xz[i] = z;
        float4* pz = (float4*)pu.p1;
        for (int i = t; i < 2 * 8 * 292 / 4; i += 256) pz[i] = z;
    }
    __syncthreads();

    // ---- stage input (2 samples), shifted +1 for the zero halo
    {
        const float4* xg = (const float4*)(x + (size_t)blockIdx.x * 2 * 784);
        for (int i = t; i < 392; i += 256) {
            float4 v = xg[i];
            int s = i / 196, q = (i - s * 196) * 4;
            float vv[4] = {v.x, v.y, v.z, v.w};
            #pragma unroll
            for (int j = 0; j < 4; j++) {
                int p = q + j, rr = p / 28, cc = p - rr * 28;
                u.xin[s][(rr + 1) * 32 + cc + 1] = vv[j];
            }
        }
    }
    __syncthreads();

    // ---- P2: conv1 + relu + pool -> p1   (wave=(s,h), lane=(ch,colgroup))
    {
        int s = w >> 1, h = w & 1;
        int g = lane & 7;
        if (g < 7) {
            const float* xb = &u.xin[s][4 * g];
            float* pout = &pu.p1[s][c1 * 292];
            for (int ii = 0; ii < 7; ii++) {
                int i = h * 7 + ii;                     // pooled row 0..13
                const float* r = xb + 2 * i * 32;
                float rv[4][6];
                #pragma unroll
                for (int dr = 0; dr < 4; dr++) {
                    float2 a = *(const float2*)(r + dr * 32);
                    float2 b = *(const float2*)(r + dr * 32 + 2);
                    float2 c2v = *(const float2*)(r + dr * 32 + 4);
                    rv[dr][0] = a.x;  rv[dr][1] = a.y;
                    rv[dr][2] = b.x;  rv[dr][3] = b.y;
                    rv[dr][4] = c2v.x; rv[dr][5] = c2v.y;
                }
                float o[2][4];
                #pragma unroll
                for (int dr = 0; dr < 2; dr++)
                    #pragma unroll
                    for (int j = 0; j < 4; j++) {
                        float acc = bias1;
                        #pragma unroll
                        for (int ky = 0; ky < 3; ky++)
                            #pragma unroll
                            for (int kx = 0; kx < 3; kx++)
                                acc = fmaf(wk1[ky * 3 + kx], rv[dr + ky][j + kx], acc);
                        o[dr][j] = acc;
                    }
                #pragma unroll
                for (int jj = 0; jj < 2; jj++) {
                    float m = fmaxf(fmaxf(o[0][2 * jj], o[0][2 * jj + 1]),
                                    fmaxf(o[1][2 * jj], o[1][2 * jj + 1]));
                    pout[(i + 1) * 18 + 1 + 2 * g + jj] = fmaxf(m, 0.f);
                }
            }
        }
    }
    __syncthreads();

    // ---- P3: conv2 + relu + pool -> u.flat (xin dead now)
    // weights from global w2q[(ci*16+c2)*12] (L1-resident, 48B/lane/ci),
    // double-buffered one ci ahead so L1 latency hides under the 72 FMAs.
    // unroll 1: keep only one ci's weights live (VGPR discipline).
    {
        int s = w >> 1, h = w & 1;
        int c2 = lane >> 2, g2 = lane & 3;
        int i0 = h * 4;                                 // h=0: i 0..3, h=1: i 4..6
        float bias = c2b[c2];
        const float4* wqb = (const float4*)w2q + c2 * 3;  // + ci*48 per channel
        float4 wa = wqb[0], wb = wqb[1], wc = wqb[2];
        float acc[4][2][4];
        #pragma unroll
        for (int ii = 0; ii < 4; ii++)
            #pragma unroll
            for (int dr = 0; dr < 2; dr++)
                #pragma unroll
                for (int j = 0; j < 4; j++) acc[ii][dr][j] = bias;

        const float* pbase = &pu.p1[s][4 * g2] + i0 * 2 * 18;
        #pragma unroll 1
        for (int ci = 0; ci < 8; ci++) {
            float wk[9] = {wa.x, wa.y, wa.z, wa.w, wb.x, wb.y, wb.z, wb.w, wc.x};
            if (ci < 7) {                               // prefetch next ci
                wa = wqb[(ci + 1) * 48];
                wb = wqb[(ci + 1) * 48 + 1];
                wc = wqb[(ci + 1) * 48 + 2];
            }
            const float* pc_ = pbase + ci * 292;
            #pragma unroll
            for (int ii = 0; ii < 4; ii++) {
                if (ii < 3 || h == 0) {
                    float rv[4][6];
                    #pragma unroll
                    for (int dr = 0; dr < 4; dr++) {
                        const float* rp = pc_ + (ii * 2 + dr) * 18;
                        float2 a = *(const float2*)rp;
                        float2 b = *(const float2*)(rp + 2);
                        float2 cc = *(const float2*)(rp + 4);
                        rv[dr][0] = a.x;  rv[dr][1] = a.y;
                        rv[dr][2] = b.x;  rv[dr][3] = b.y;
                        rv[dr][4] = cc.x; rv[dr][5] = cc.y;
                    }
                    #pragma unroll
                    for (int dr = 0; dr < 2; dr++)
                        #pragma unroll
                        for (int j = 0; j < 4; j++) {
                            float a2 = acc[ii][dr][j];
                            #pragma unroll
                            for (int ky = 0; ky < 3; ky++)
                                #pragma unroll
                                for (int kx = 0; kx < 3; kx++)
                                    a2 = fmaf(wk[ky * 3 + kx], rv[dr + ky][j + kx], a2);
                            acc[ii][dr][j] = a2;
                        }
                }
            }
        }
        #pragma unroll
        for (int ii = 0; ii < 4; ii++) {
            if (ii < 3 || h == 0) {
                int i = i0 + ii;
                #pragma unroll
                for (int jj = 0; jj < 2; jj++) {
                    int pc = 2 * g2 + jj;
                    if (pc < 7) {
                        float m = fmaxf(fmaxf(acc[ii][0][2 * jj], acc[ii][0][2 * jj + 1]),
                                        fmaxf(acc[ii][1][2 * jj], acc[ii][1][2 * jj + 1]));
                        u.flat[s][c2 * 49 + i * 7 + pc] = fmaxf(m, 0.f);
                    }
                }
            }
        }
    }
    __syncthreads();   // p1 dead from here; pu.fc live

    // ---- P5: fc1 partials. Each wave owns g-quarter [w*49, w*49+49) for
    // BOTH samples: one weight float4 feeds 2 FMA chains -> halved L2
    // traffic (200KB/block). 4 independent chains deepen in-flight loads.
    {
        const float* fl0 = u.flat[0];
        const float* fl1 = u.flat[1];
        const float4* wp4 = (const float4*)wT2 + lane;   // + g*64 per k4-group
        int g0 = w * 49;
        float a00 = 0.f, a01 = 0.f, a10 = 0.f, a11 = 0.f;
        #pragma unroll 2
        for (int g = g0; g < g0 + 48; g += 2) {
            float4 wv0 = wp4[(size_t)g * 64];
            float4 wv1 = wp4[(size_t)(g + 1) * 64];
            float4 f00 = *(const float4*)&fl0[4 * g];
            float4 f10 = *(const float4*)&fl1[4 * g];
            float4 f01 = *(const float4*)&fl0[4 * g + 4];
            float4 f11 = *(const float4*)&fl1[4 * g + 4];
            a00 = fmaf(f00.x, wv0.x, fmaf(f00.y, wv0.y, fmaf(f00.z, wv0.z, fmaf(f00.w, wv0.w, a00))));
            a10 = fmaf(f10.x, wv0.x, fmaf(f10.y, wv0.y, fmaf(f10.z, wv0.z, fmaf(f10.w, wv0.w, a10))));
            a01 = fmaf(f01.x, wv1.x, fmaf(f01.y, wv1.y, fmaf(f01.z, wv1.z, fmaf(f01.w, wv1.w, a01))));
            a11 = fmaf(f11.x, wv1.x, fmaf(f11.y, wv1.y, fmaf(f11.z, wv1.z, fmaf(f11.w, wv1.w, a11))));
        }
        {   // tail g0+48 (49 groups per quarter)
            int g = g0 + 48;
            float4 wv = wp4[(size_t)g * 64];
            float4 f0 = *(const float4*)&fl0[4 * g];
            float4 f1 = *(const float4*)&fl1[4 * g];
            a00 = fmaf(f0.x, wv.x, fmaf(f0.y, wv.y, fmaf(f0.z, wv.z, fmaf(f0.w, wv.w, a00))));
            a10 = fmaf(f1.x, wv.x, fmaf(f1.y, wv.y, fmaf(f1.z, wv.z, fmaf(f1.w, wv.w, a10))));
        }
        pu.fc.part[0][w][lane] = a00 + a01;
        pu.fc.part[1][w][lane] = a10 + a11;
    }
    __syncthreads();

    // ---- P6: combine quarters + bias + relu
    if (t < 128) {
        int s2 = t >> 6, o = t & 63;
        float h = pu.fc.part[s2][0][o] + pu.fc.part[s2][1][o]
                + pu.fc.part[s2][2][o] + pu.fc.part[s2][3][o] + f1b[o];
        pu.fc.hs[s2][o] = fmaxf(h, 0.f);
    }
    __syncthreads();

    // ---- P7: fc2 + feat + sharded BN stats
    if (t < 8) {
        int s = t >> 2, j = t & 3;
        float a = f2bias[j];
        #pragma unroll
        for (int o = 0; o < 64; o++) a = fmaf(pu.fc.hs[s][o], f2w[j * 64 + o], a);
        feat[((size_t)blockIdx.x * 2 + s) * 4 + j] = a;
        int g = blockIdx.x & 63;
        atomicAdd(&stats[g * 8 + j], a);
        atomicAdd(&stats[g * 8 + 4 + j], a * a);
    }
}

// ---------------- BN + encoder + U matvec + PauliZ measure ------------------
// 4 lanes per sample (each does 4 rows of the 16x16 matvec, shfl-reduce),
// grid = B/32 blocks -> 256 blocks (was 64: only 1/4 of the CUs active).
__global__ __launch_bounds__(128) void quantum_kernel(
    const float* __restrict__ feat, const float* __restrict__ Ug,
    const float* __restrict__ stats, const float* __restrict__ bn_g,
    const float* __restrict__ bn_b, float* __restrict__ out, int B)
{
    __shared__ float2 Us[256];
    __shared__ float sm[8];
    int t = threadIdx.x;                  // 128 threads
    for (int i = t; i < 256; i += 128) Us[i] = ((const float2*)Ug)[i];
    if (t < 8) sm[t] = 0.f;
    __syncthreads();
    {   // parallel gather of 64 shards x 8 (index mod 8 preserved by +128)
        float v = stats[t] + stats[t + 128] + stats[t + 256] + stats[t + 384];
        atomicAdd(&sm[t & 7], v);
    }
    __syncthreads();
    int q = t & 3;                        // row-quad within the sample
    int s = blockIdx.x * 32 + (t >> 2);
    float4 fv = ((const float4*)feat)[s];
    float f[4] = {fv.x, fv.y, fv.z, fv.w};
    float cn[4], sn[4];
    float invB = 1.0f / (float)B;
    #pragma unroll
    for (int w = 0; w < 4; w++) {
        float mean = sm[w] * invB;
        float var  = sm[4 + w] * invB - mean * mean;
        float fh = (f[w] - mean) / sqrtf(var + B_EPS) * bn_g[w] + bn_b[w];
        cn[w] = cosf(0.5f * fh);
        sn[w] = sinf(0.5f * fh);
    }
    // encoded product state: s0_k = prod(c/s) * (-i)^popcount(k)
    float re0[16], im0[16];
    #pragma unroll
    for (int k = 0; k < 16; k++) {
        float mag = ((k & 8) ? sn[0] : cn[0]) * ((k & 4) ? sn[1] : cn[1]) *
                    ((k & 2) ? sn[2] : cn[2]) * ((k & 1) ? sn[3] : cn[3]);
        int m = __popc(k) & 3;
        re0[k] = (m == 0) ? mag : (m == 2) ? -mag : 0.f;
        im0[k] = (m == 1) ? -mag : (m == 3) ? mag : 0.f;
    }
    float o0 = 0.f, o1 = 0.f, o2 = 0.f, o3 = 0.f;
    #pragma unroll
    for (int i = 0; i < 4; i++) {
        int r = q * 4 + i;
        float ar = 0.f, ai = 0.f;
        #pragma unroll
        for (int k = 0; k < 16; k++) {
            float2 uu = Us[r * 16 + k];
            ar += uu.x * re0[k] - uu.y * im0[k];
            ai += uu.x * im0[k] + uu.y * re0[k];
        }
        float p = ar * ar + ai * ai;
        o0 += (r & 8) ? -p : p;
        o1 += (r & 4) ? -p : p;
        o2 += (r & 2) ? -p : p;
        o3 += (r & 1) ? -p : p;
    }
    // reduce across the 4-lane group
    o0 += __shfl_xor(o0, 1);  o0 += __shfl_xor(o0, 2);
    o1 += __shfl_xor(o1, 1);  o1 += __shfl_xor(o1, 2);
    o2 += __shfl_xor(o2, 1);  o2 += __shfl_xor(o2, 2);
    o3 += __shfl_xor(o3, 1);  o3 += __shfl_xor(o3, 2);
    if (q == 0) {
        float4 ov = {o0, o1, o2, o3};
        ((float4*)out)[s] = ov;
    }
}

// ---------------------------------------------------------------------------
extern "C" void kernel_launch(void* const* d_in, const int* in_sizes, int n_in,
                              void* d_out, int out_size, void* d_ws, size_t ws_size,
                              hipStream_t stream)
{
    const float* x   = (const float*)d_in[0];
    const float* c1w = (const float*)d_in[1];
    const float* c1b = (const float*)d_in[2];
    const float* c2w = (const float*)d_in[3];
    const float* c2b = (const float*)d_in[4];
    const float* f1w = (const float*)d_in[5];
    const float* f1b = (const float*)d_in[6];
    const float* f2w = (const float*)d_in[7];
    const float* f2b = (const float*)d_in[8];
    const float* bng = (const float*)d_in[9];
    const float* bnb = (const float*)d_in[10];
    const float* rl  = (const float*)d_in[11];
    float* out = (float*)d_out;

    int B = in_sizes[0] / 784;

    float* wsf   = (float*)d_ws;
    float* feat  = wsf;                          // B*4
    float* wT2   = feat + (size_t)B * 4;         // 784*64 (as [k4][64][4])
    float* U     = wT2 + 784 * 64;               // 512 (float2[256])
    float* stats = U + 512;                      // 512 (64 shards x 8)
    float* w2q   = stats + 512;                  // 1536 ([ci][c2][12], q<9 used)

    prep_kernel<<<197, 256, 0, stream>>>(rl, f1w, c2w, U, wT2, w2q, stats);
    conv_kernel<<<B / 2, 256, 0, stream>>>(x, c1w, c1b, w2q, c2b, wT2,
                                           f1b, f2w, f2b, feat, stats);
    quantum_kernel<<<B / 32, 128, 0, stream>>>(feat, U, stats, bng, bnb, out, B);
}

// Round 3
// 190.383 us; speedup vs baseline: 4.8131x; 1.0613x over previous
//
#include <hip/hip_runtime.h>

// ---------------------------------------------------------------------------
// QuantumImageEncoder R14: sample-pair packed FP32 (v_pk_fma_f32).
//  R13 post-mortem: conv=115us, VALUBusy~80%, HBM 1.6% -> issue-bound.
//  Only ~30% of issue slots are FMA, and all FMAs are scalar. gfx950's
//  157 TF FP32 peak requires packed v_pk_fma_f32 (VOP3P).
//  R14 interleaves the block's two samples as float2 in all LDS tiles and
//  uses __builtin_elementwise_fma on a 2-float ext-vector: each conv/fc FMA
//  instruction now computes BOTH samples (halves FMA instrs, halves LDS
//  read instrs per sample). Waves split spatial rows instead of samples.
//  Rolling-row window in P2/P3 keeps VGPR live-set small (R12 lesson).
//  LDS = 7680(xin2) + 18560(p1, row stride 18 f2 for the g2=3 overread,
//  ch stride 290 f2 for bank spread) = 26.2KB -> 6 blocks/CU kept.
// ---------------------------------------------------------------------------

#define B_EPS 1e-5f

typedef float f2 __attribute__((ext_vector_type(2)));

__device__ __forceinline__ f2 sp(float x)          { f2 r; r.x = x; r.y = x; return r; }
__device__ __forceinline__ f2 mk(float a, float b) { f2 r; r.x = a; r.y = b; return r; }
#define PKFMA(a, b, c) __builtin_elementwise_fma(a, b, c)
#define PKMAX(a, b)    __builtin_elementwise_max(a, b)

// 3-tap conv row update: acc[j] += wp[0..2] * rv[j..j+2]  (packed, 2 samples)
__device__ __forceinline__ void row_fma(f2* acc, const float* wp, const f2* rv)
{
    #pragma unroll
    for (int j = 0; j < 4; j++) {
        acc[j] = PKFMA(sp(wp[0]), rv[j],     acc[j]);
        acc[j] = PKFMA(sp(wp[1]), rv[j + 1], acc[j]);
        acc[j] = PKFMA(sp(wp[2]), rv[j + 2], acc[j]);
    }
}

// ---------------- prep: U build + stats zero + conv2-weight repack (block 0),
// ----------------       fc1_w -> wT2[k4][64][4] (blocks 1..196) -------------
__global__ void prep_kernel(const float* __restrict__ rl,
                            const float* __restrict__ f1w,
                            const float* __restrict__ c2w,
                            float* __restrict__ Uout,
                            float* __restrict__ wT2,
                            float* __restrict__ w2q,
                            float* __restrict__ stats)
{
    if (blockIdx.x == 0) {
        __shared__ float2 U[16][16];
        int t = threadIdx.x;                 // 256 threads
        int r = t >> 4, cc = t & 15;
        U[r][cc] = (r == cc) ? make_float2(1.f, 0.f) : make_float2(0.f, 0.f);
        stats[t] = 0.f;                      // 512-float sharded stats
        stats[t + 256] = 0.f;
        // conv2 weights -> w2q[(ci*16+c2)*12 + q], q<9 valid, float4-aligned
        for (int i = t; i < 16 * 8 * 12; i += 256) {
            int ci = i / 192, rem = i - ci * 192;
            int c2 = rem / 12, qq = rem - c2 * 12;
            w2q[i] = (qq < 9) ? c2w[c2 * 72 + ci * 9 + qq] : 0.f;
        }
        __syncthreads();
        for (int op = 0; op < 30; op++) {
            int kind = op & 3;               // 0=rx,1=ry,2=rz,3=cnot ; wire = op%4
            float2 cur = U[r][cc];
            float2 nv;
            if (kind == 3) {
                float2 part = U[r ^ 8][cc];  // control wire3 (bit 1), target wire0 (bit 8)
                nv = (r & 1) ? part : cur;
            } else {
                int m = 8 >> kind;           // wire w=kind -> bit (3-w)
                float theta = rl[op - (op >> 2)];
                float ch = cosf(0.5f * theta), sh = sinf(0.5f * theta);
                float2 part = U[r ^ m][cc];
                int br = (r & m) ? 1 : 0;
                float2 gc, gp;
                if (kind == 0)      { gc = make_float2(ch, 0.f);           gp = make_float2(0.f, -sh); }
                else if (kind == 1) { gc = make_float2(ch, 0.f);           gp = make_float2(br ? sh : -sh, 0.f); }
                else                { gc = make_float2(ch, br ? sh : -sh); gp = make_float2(0.f, 0.f); }
                nv.x = gc.x*cur.x - gc.y*cur.y + gp.x*part.x - gp.y*part.y;
                nv.y = gc.x*cur.y + gc.y*cur.x + gp.x*part.y + gp.y*part.x;
            }
            __syncthreads();
            U[r][cc] = nv;
            __syncthreads();
        }
        ((float2*)Uout)[t] = U[r][cc];
    } else {
        int id = (blockIdx.x - 1) * 256 + threadIdx.x;
        if (id < 784 * 64) {
            int k = id >> 6, o = id & 63;
            // wT2 float index = (k4*64 + o)*4 + (k&3)
            wT2[(((k >> 2) * 64 + o) << 2) + (k & 3)] = f1w[o * 784 + k];
        }
    }
}

// ---------------- conv backbone + fused fc: 2 samples / block, 4 waves ------
// All activations are f2 = (sample0, sample1). One packed FMA covers both.
__global__ __launch_bounds__(256) void conv_kernel(
    const float* __restrict__ x,  const float* __restrict__ c1w,
    const float* __restrict__ c1b, const float* __restrict__ w2q,
    const float* __restrict__ c2b, const float* __restrict__ wT2,
    const float* __restrict__ f1b, const float* __restrict__ f2w,
    const float* __restrict__ f2bias, float* __restrict__ feat,
    float* __restrict__ stats)
{
    __shared__ union alignas(16) {
        f2 xin[30 * 32];           // [row 0..29][colidx 0..31]; col c -> idx c+2
        f2 flat[784];              // conv2 pooled output, idx = c2*49 + i*7 + pc
    } u;
    __shared__ union alignas(16) {
        f2 p1[8 * 290];            // [ch][row 0..15 (stride 18)][colidx]; +2 pad/ch
        struct { f2 part[4][64]; f2 hs[64]; } fc;   // p1 dead after P3
    } pu;

    int t = threadIdx.x;
    int w = t >> 6, lane = t & 63;

    // conv1 weights for this lane (8 lanes share an address -> L1 broadcast)
    int c1 = lane >> 3;
    float wk1[9];
    #pragma unroll
    for (int q = 0; q < 9; q++) wk1[q] = c1w[c1 * 9 + q];
    float bias1 = c1b[c1];

    // ---- P1: zero xin + p1 (halo correctness)
    {
        float4 z = make_float4(0.f, 0.f, 0.f, 0.f);
        float4* xz = (float4*)u.xin;
        for (int i = t; i < 480; i += 256) xz[i] = z;       // 960 f2
        float4* pz = (float4*)pu.p1;
        for (int i = t; i < 1160; i += 256) pz[i] = z;      // 2320 f2
    }
    __syncthreads();

    // ---- stage input: both samples interleaved, 2 float4 writes / position
    {
        const float4* xg0 = (const float4*)(x + (size_t)blockIdx.x * 2 * 784);
        const float4* xg1 = xg0 + 196;
        if (t < 196) {
            float4 v0 = xg0[t];
            float4 v1 = xg1[t];
            int p = 4 * t, rr = p / 28, cb = p - rr * 28;   // cb in {0,4,...,24}
            float4* dst = (float4*)&u.xin[(rr + 1) * 32 + cb + 2];
            dst[0] = make_float4(v0.x, v1.x, v0.y, v1.y);
            dst[1] = make_float4(v0.z, v1.z, v0.w, v1.w);
        }
    }
    __syncthreads();

    // ---- P2: conv1 + relu + pool -> p1. wave w owns pooled rows {w+4k}.
    // lane=(c1,g): channel c1, 4-col group g (g<7). Rolling input-row window.
    {
        int g = lane & 7;
        if (g < 7) {
            const f2* xb = &u.xin[4 * g + 1];
            f2* pout = &pu.p1[c1 * 290 + 1];
            #pragma unroll 1
            for (int k = 0; k < 4; k++) {
                int i = w + 4 * k;                          // pooled row 0..13
                if (i > 13) break;
                f2 o_[2][4];
                #pragma unroll
                for (int dr = 0; dr < 2; dr++)
                    #pragma unroll
                    for (int j = 0; j < 4; j++) o_[dr][j] = sp(bias1);
                #pragma unroll
                for (int q = 0; q < 4; q++) {               // input row 2i+q
                    f2 rv[6];
                    const f2* rp = xb + (2 * i + q) * 32;
                    #pragma unroll
                    for (int m = 0; m < 6; m++) rv[m] = rp[m];
                    if (q < 3)  row_fma(o_[0], &wk1[q * 3], rv);        // dr=0, ky=q
                    if (q >= 1) row_fma(o_[1], &wk1[(q - 1) * 3], rv);  // dr=1, ky=q-1
                }
                #pragma unroll
                for (int jj = 0; jj < 2; jj++) {
                    f2 m = PKMAX(PKMAX(o_[0][2 * jj], o_[0][2 * jj + 1]),
                                 PKMAX(o_[1][2 * jj], o_[1][2 * jj + 1]));
                    pout[(i + 1) * 18 + 2 * g + jj] = PKMAX(m, sp(0.f));
                }
            }
        }
    }
    __syncthreads();

    // ---- P3: conv2 + relu + pool -> u.flat (xin dead). wave w owns pooled
    // rows {w, w+4}. lane=(c2,g2). Weights from global w2q (L1), prefetched.
    {
        int c2 = lane >> 2, g2 = lane & 3;
        float bias2 = c2b[c2];
        const float4* wqb = (const float4*)w2q + c2 * 3;    // + ci*48 per ci
        #pragma unroll 1
        for (int k = 0; k < 2; k++) {
            int i = w + 4 * k;                              // pooled row 0..6
            if (i > 6) break;
            f2 acc[2][4];
            #pragma unroll
            for (int dr = 0; dr < 2; dr++)
                #pragma unroll
                for (int j = 0; j < 4; j++) acc[dr][j] = sp(bias2);
            float4 wa = wqb[0], wb = wqb[1], wc = wqb[2];
            #pragma unroll 1
            for (int ci = 0; ci < 8; ci++) {
                float wk[9] = {wa.x, wa.y, wa.z, wa.w, wb.x, wb.y, wb.z, wb.w, wc.x};
                if (ci < 7) {                               // prefetch next ci
                    wa = wqb[(ci + 1) * 48];
                    wb = wqb[(ci + 1) * 48 + 1];
                    wc = wqb[(ci + 1) * 48 + 2];
                }
                const f2* pc_ = &pu.p1[ci * 290 + (2 * i) * 18 + 4 * g2];
                #pragma unroll
                for (int q = 0; q < 4; q++) {               // p1 row 2i+q
                    f2 rv[6];
                    const f2* rp = pc_ + q * 18;
                    #pragma unroll
                    for (int m = 0; m < 6; m++) rv[m] = rp[m];
                    if (q < 3)  row_fma(acc[0], &wk[q * 3], rv);
                    if (q >= 1) row_fma(acc[1], &wk[(q - 1) * 3], rv);
                }
            }
            #pragma unroll
            for (int jj = 0; jj < 2; jj++) {
                int pc = 2 * g2 + jj;
                if (pc < 7) {
                    f2 m = PKMAX(PKMAX(acc[0][2 * jj], acc[0][2 * jj + 1]),
                                 PKMAX(acc[1][2 * jj], acc[1][2 * jj + 1]));
                    u.flat[c2 * 49 + i * 7 + pc] = PKMAX(m, sp(0.f));
                }
            }
        }
    }
    __syncthreads();   // p1 dead from here; pu.fc live

    // ---- P5: fc1 partials. wave owns g-quarter [w*49, w*49+49); weight
    // float4 (global, read once/block) feeds one packed chain for 2 samples.
    {
        const f2* fl = u.flat;
        const float4* wp4 = (const float4*)wT2 + lane;      // + g*64 per k4-group
        int g0 = w * 49;
        f2 a0 = sp(0.f), a1 = sp(0.f);
        #pragma unroll 2
        for (int g = g0; g < g0 + 48; g += 2) {
            float4 wv0 = wp4[(size_t)g * 64];
            float4 wv1 = wp4[(size_t)(g + 1) * 64];
            float4 fA = *(const float4*)&fl[4 * g];
            float4 fB = *(const float4*)&fl[4 * g + 2];
            float4 fC = *(const float4*)&fl[4 * g + 4];
            float4 fD = *(const float4*)&fl[4 * g + 6];
            a0 = PKFMA(sp(wv0.x), mk(fA.x, fA.y), a0);
            a0 = PKFMA(sp(wv0.y), mk(fA.z, fA.w), a0);
            a0 = PKFMA(sp(wv0.z), mk(fB.x, fB.y), a0);
            a0 = PKFMA(sp(wv0.w), mk(fB.z, fB.w), a0);
            a1 = PKFMA(sp(wv1.x), mk(fC.x, fC.y), a1);
            a1 = PKFMA(sp(wv1.y), mk(fC.z, fC.w), a1);
            a1 = PKFMA(sp(wv1.z), mk(fD.x, fD.y), a1);
            a1 = PKFMA(sp(wv1.w), mk(fD.z, fD.w), a1);
        }
        {   // tail group g0+48
            int g = g0 + 48;
            float4 wv = wp4[(size_t)g * 64];
            float4 fA = *(const float4*)&fl[4 * g];
            float4 fB = *(const float4*)&fl[4 * g + 2];
            a0 = PKFMA(sp(wv.x), mk(fA.x, fA.y), a0);
            a0 = PKFMA(sp(wv.y), mk(fA.z, fA.w), a0);
            a0 = PKFMA(sp(wv.z), mk(fB.x, fB.y), a0);
            a0 = PKFMA(sp(wv.w), mk(fB.z, fB.w), a0);
        }
        pu.fc.part[w][lane] = a0 + a1;
    }
    __syncthreads();

    // ---- P6: combine quarters + bias + relu (both samples packed)
    if (t < 64) {
        f2 h = pu.fc.part[0][t] + pu.fc.part[1][t]
             + pu.fc.part[2][t] + pu.fc.part[3][t] + sp(f1b[t]);
        pu.fc.hs[t] = PKMAX(h, sp(0.f));
    }
    __syncthreads();

    // ---- P7: fc2 + feat + sharded BN stats (packed: .x=s0, .y=s1)
    if (t < 4) {
        int j = t;
        f2 a = sp(f2bias[j]);
        #pragma unroll
        for (int o = 0; o < 64; o++) a = PKFMA(sp(f2w[j * 64 + o]), pu.fc.hs[o], a);
        feat[((size_t)blockIdx.x * 2 + 0) * 4 + j] = a.x;
        feat[((size_t)blockIdx.x * 2 + 1) * 4 + j] = a.y;
        int g = blockIdx.x & 63;
        atomicAdd(&stats[g * 8 + j], a.x + a.y);
        atomicAdd(&stats[g * 8 + 4 + j], a.x * a.x + a.y * a.y);
    }
}

// ---------------- BN + encoder + U matvec + PauliZ measure ------------------
// 4 lanes per sample (each does 4 rows of the 16x16 matvec, shfl-reduce).
__global__ __launch_bounds__(128) void quantum_kernel(
    const float* __restrict__ feat, const float* __restrict__ Ug,
    const float* __restrict__ stats, const float* __restrict__ bn_g,
    const float* __restrict__ bn_b, float* __restrict__ out, int B)
{
    __shared__ float2 Us[256];
    __shared__ float sm[8];
    int t = threadIdx.x;                  // 128 threads
    for (int i = t; i < 256; i += 128) Us[i] = ((const float2*)Ug)[i];
    if (t < 8) sm[t] = 0.f;
    __syncthreads();
    {   // parallel gather of 64 shards x 8 (index mod 8 preserved by +128)
        float v = stats[t] + stats[t + 128] + stats[t + 256] + stats[t + 384];
        atomicAdd(&sm[t & 7], v);
    }
    __syncthreads();
    int q = t & 3;                        // row-quad within the sample
    int s = blockIdx.x * 32 + (t >> 2);
    float4 fv = ((const float4*)feat)[s];
    float f[4] = {fv.x, fv.y, fv.z, fv.w};
    float cn[4], sn[4];
    float invB = 1.0f / (float)B;
    #pragma unroll
    for (int w = 0; w < 4; w++) {
        float mean = sm[w] * invB;
        float var  = sm[4 + w] * invB - mean * mean;
        float fh = (f[w] - mean) / sqrtf(var + B_EPS) * bn_g[w] + bn_b[w];
        cn[w] = cosf(0.5f * fh);
        sn[w] = sinf(0.5f * fh);
    }
    // encoded product state: s0_k = prod(c/s) * (-i)^popcount(k)
    float re0[16], im0[16];
    #pragma unroll
    for (int k = 0; k < 16; k++) {
        float mag = ((k & 8) ? sn[0] : cn[0]) * ((k & 4) ? sn[1] : cn[1]) *
                    ((k & 2) ? sn[2] : cn[2]) * ((k & 1) ? sn[3] : cn[3]);
        int m = __popc(k) & 3;
        re0[k] = (m == 0) ? mag : (m == 2) ? -mag : 0.f;
        im0[k] = (m == 1) ? -mag : (m == 3) ? mag : 0.f;
    }
    float o0 = 0.f, o1 = 0.f, o2 = 0.f, o3 = 0.f;
    #pragma unroll
    for (int i = 0; i < 4; i++) {
        int r = q * 4 + i;
        float ar = 0.f, ai = 0.f;
        #pragma unroll
        for (int k = 0; k < 16; k++) {
            float2 uu = Us[r * 16 + k];
            ar += uu.x * re0[k] - uu.y * im0[k];
            ai += uu.x * im0[k] + uu.y * re0[k];
        }
        float p = ar * ar + ai * ai;
        o0 += (r & 8) ? -p : p;
        o1 += (r & 4) ? -p : p;
        o2 += (r & 2) ? -p : p;
        o3 += (r & 1) ? -p : p;
    }
    // reduce across the 4-lane group
    o0 += __shfl_xor(o0, 1);  o0 += __shfl_xor(o0, 2);
    o1 += __shfl_xor(o1, 1);  o1 += __shfl_xor(o1, 2);
    o2 += __shfl_xor(o2, 1);  o2 += __shfl_xor(o2, 2);
    o3 += __shfl_xor(o3, 1);  o3 += __shfl_xor(o3, 2);
    if (q == 0) {
        float4 ov = {o0, o1, o2, o3};
        ((float4*)out)[s] = ov;
    }
}

// ---------------------------------------------------------------------------
extern "C" void kernel_launch(void* const* d_in, const int* in_sizes, int n_in,
                              void* d_out, int out_size, void* d_ws, size_t ws_size,
                              hipStream_t stream)
{
    const float* x   = (const float*)d_in[0];
    const float* c1w = (const float*)d_in[1];
    const float* c1b = (const float*)d_in[2];
    const float* c2w = (const float*)d_in[3];
    const float* c2b = (const float*)d_in[4];
    const float* f1w = (const float*)d_in[5];
    const float* f1b = (const float*)d_in[6];
    const float* f2w = (const float*)d_in[7];
    const float* f2b = (const float*)d_in[8];
    const float* bng = (const float*)d_in[9];
    const float* bnb = (const float*)d_in[10];
    const float* rl  = (const float*)d_in[11];
    float* out = (float*)d_out;

    int B = in_sizes[0] / 784;

    float* wsf   = (float*)d_ws;
    float* feat  = wsf;                          // B*4
    float* wT2   = feat + (size_t)B * 4;         // 784*64 (as [k4][64][4])
    float* U     = wT2 + 784 * 64;               // 512 (float2[256])
    float* stats = U + 512;                      // 512 (64 shards x 8)
    float* w2q   = stats + 512;                  // 1536 ([ci][c2][12], q<9 used)

    prep_kernel<<<197, 256, 0, stream>>>(rl, f1w, c2w, U, wT2, w2q, stats);
    conv_kernel<<<B / 2, 256, 0, stream>>>(x, c1w, c1b, w2q, c2b, wT2,
                                           f1b, f2w, f2b, feat, stats);
    quantum_kernel<<<B / 32, 128, 0, stream>>>(feat, U, stats, bng, bnb, out, B);
}

// Round 4
// 185.700 us; speedup vs baseline: 4.9344x; 1.0252x over previous
//
#include <hip/hip_runtime.h>

// ---------------------------------------------------------------------------
// QuantumImageEncoder R15: b128 LDS reads via aligned col layouts.
//  R14 post-mortem: packed FMA confirmed (conv 115->95us) but kernel became
//  LDS-issue bound: ~480 ds_read_b64/thread vs ~1150 packed FMA. Every conv
//  row window is 6 consecutive f2 (48B) but started at an ODD f2 index
//  (halo col -1), forcing b64 reads.
//  R15 shifts both tiles so col c -> idx c+3: window base = 4g+2 (even, 16B
//  aligned) -> 3x ds_read_b128 per row (halves DS read instrs, 480->240).
//  Reads stay broadcast (addr depends on col-group only). P3's 2-f2 overrun
//  at g2=3 lands in the next row's zero halo and feeds only discarded
//  outputs. Staging writes become 4x b64 (odd base). Everything else = R14.
// ---------------------------------------------------------------------------

#define B_EPS 1e-5f

typedef float f2 __attribute__((ext_vector_type(2)));

__device__ __forceinline__ f2 sp(float x)          { f2 r; r.x = x; r.y = x; return r; }
__device__ __forceinline__ f2 mk(float a, float b) { f2 r; r.x = a; r.y = b; return r; }
#define PKFMA(a, b, c) __builtin_elementwise_fma(a, b, c)
#define PKMAX(a, b)    __builtin_elementwise_max(a, b)

// 3-tap conv row update: acc[j] += wp[0..2] * rv[j..j+2]  (packed, 2 samples)
__device__ __forceinline__ void row_fma(f2* acc, const float* wp, const f2* rv)
{
    #pragma unroll
    for (int j = 0; j < 4; j++) {
        acc[j] = PKFMA(sp(wp[0]), rv[j],     acc[j]);
        acc[j] = PKFMA(sp(wp[1]), rv[j + 1], acc[j]);
        acc[j] = PKFMA(sp(wp[2]), rv[j + 2], acc[j]);
    }
}

// load 6 consecutive f2 from 16B-aligned base as 3x b128
__device__ __forceinline__ void load_rv6(f2* rv, const f2* rp)
{
    float4 A = *(const float4*)rp;
    float4 Bv = *(const float4*)(rp + 2);
    float4 Cv = *(const float4*)(rp + 4);
    rv[0] = mk(A.x, A.y);   rv[1] = mk(A.z, A.w);
    rv[2] = mk(Bv.x, Bv.y); rv[3] = mk(Bv.z, Bv.w);
    rv[4] = mk(Cv.x, Cv.y); rv[5] = mk(Cv.z, Cv.w);
}

// ---------------- prep: U build + stats zero + conv2-weight repack (block 0),
// ----------------       fc1_w -> wT2[k4][64][4] (blocks 1..196) -------------
__global__ void prep_kernel(const float* __restrict__ rl,
                            const float* __restrict__ f1w,
                            const float* __restrict__ c2w,
                            float* __restrict__ Uout,
                            float* __restrict__ wT2,
                            float* __restrict__ w2q,
                            float* __restrict__ stats)
{
    if (blockIdx.x == 0) {
        __shared__ float2 U[16][16];
        int t = threadIdx.x;                 // 256 threads
        int r = t >> 4, cc = t & 15;
        U[r][cc] = (r == cc) ? make_float2(1.f, 0.f) : make_float2(0.f, 0.f);
        stats[t] = 0.f;                      // 512-float sharded stats
        stats[t + 256] = 0.f;
        // conv2 weights -> w2q[(ci*16+c2)*12 + q], q<9 valid, float4-aligned
        for (int i = t; i < 16 * 8 * 12; i += 256) {
            int ci = i / 192, rem = i - ci * 192;
            int c2 = rem / 12, qq = rem - c2 * 12;
            w2q[i] = (qq < 9) ? c2w[c2 * 72 + ci * 9 + qq] : 0.f;
        }
        __syncthreads();
        for (int op = 0; op < 30; op++) {
            int kind = op & 3;               // 0=rx,1=ry,2=rz,3=cnot ; wire = op%4
            float2 cur = U[r][cc];
            float2 nv;
            if (kind == 3) {
                float2 part = U[r ^ 8][cc];  // control wire3 (bit 1), target wire0 (bit 8)
                nv = (r & 1) ? part : cur;
            } else {
                int m = 8 >> kind;           // wire w=kind -> bit (3-w)
                float theta = rl[op - (op >> 2)];
                float ch = cosf(0.5f * theta), sh = sinf(0.5f * theta);
                float2 part = U[r ^ m][cc];
                int br = (r & m) ? 1 : 0;
                float2 gc, gp;
                if (kind == 0)      { gc = make_float2(ch, 0.f);           gp = make_float2(0.f, -sh); }
                else if (kind == 1) { gc = make_float2(ch, 0.f);           gp = make_float2(br ? sh : -sh, 0.f); }
                else                { gc = make_float2(ch, br ? sh : -sh); gp = make_float2(0.f, 0.f); }
                nv.x = gc.x*cur.x - gc.y*cur.y + gp.x*part.x - gp.y*part.y;
                nv.y = gc.x*cur.y + gc.y*cur.x + gp.x*part.y + gp.y*part.x;
            }
            __syncthreads();
            U[r][cc] = nv;
            __syncthreads();
        }
        ((float2*)Uout)[t] = U[r][cc];
    } else {
        int id = (blockIdx.x - 1) * 256 + threadIdx.x;
        if (id < 784 * 64) {
            int k = id >> 6, o = id & 63;
            // wT2 float index = (k4*64 + o)*4 + (k&3)
            wT2[(((k >> 2) * 64 + o) << 2) + (k & 3)] = f1w[o * 784 + k];
        }
    }
}

// ---------------- conv backbone + fused fc: 2 samples / block, 4 waves ------
// All activations are f2 = (sample0, sample1). One packed FMA covers both.
// Tiles store col c at idx c+3 so conv windows (col-1..col+4) are 16B-aligned.
__global__ __launch_bounds__(256) void conv_kernel(
    const float* __restrict__ x,  const float* __restrict__ c1w,
    const float* __restrict__ c1b, const float* __restrict__ w2q,
    const float* __restrict__ c2b, const float* __restrict__ wT2,
    const float* __restrict__ f1b, const float* __restrict__ f2w,
    const float* __restrict__ f2bias, float* __restrict__ feat,
    float* __restrict__ stats)
{
    __shared__ union alignas(16) {
        f2 xin[30 * 32];           // [row 0..29][idx]; col c -> idx c+3, halo zeros
        f2 flat[784];              // conv2 pooled output, idx = c2*49 + i*7 + pc
    } u;
    __shared__ union alignas(16) {
        f2 p1[8 * 290];            // [ch][row 0..15 (stride 18)][idx]; col c -> idx c+3
        struct { f2 part[4][64]; f2 hs[64]; } fc;   // p1 dead after P3
    } pu;

    int t = threadIdx.x;
    int w = t >> 6, lane = t & 63;

    // conv1 weights for this lane (8 lanes share an address -> L1 broadcast)
    int c1 = lane >> 3;
    float wk1[9];
    #pragma unroll
    for (int q = 0; q < 9; q++) wk1[q] = c1w[c1 * 9 + q];
    float bias1 = c1b[c1];

    // ---- P1: zero xin + p1 (halo correctness)
    {
        float4 z = make_float4(0.f, 0.f, 0.f, 0.f);
        float4* xz = (float4*)u.xin;
        for (int i = t; i < 480; i += 256) xz[i] = z;       // 960 f2
        float4* pz = (float4*)pu.p1;
        for (int i = t; i < 1160; i += 256) pz[i] = z;      // 2320 f2
    }
    __syncthreads();

    // ---- stage input: both samples interleaved (col c -> idx c+3)
    {
        const float4* xg0 = (const float4*)(x + (size_t)blockIdx.x * 2 * 784);
        const float4* xg1 = xg0 + 196;
        if (t < 196) {
            float4 v0 = xg0[t];
            float4 v1 = xg1[t];
            int p = 4 * t, rr = p / 28, cb = p - rr * 28;   // cb in {0,4,...,24}
            f2* dst = &u.xin[(rr + 1) * 32 + cb + 3];
            dst[0] = mk(v0.x, v1.x);
            dst[1] = mk(v0.y, v1.y);
            dst[2] = mk(v0.z, v1.z);
            dst[3] = mk(v0.w, v1.w);
        }
    }
    __syncthreads();

    // ---- P2: conv1 + relu + pool -> p1. wave w owns pooled rows {w+4k}.
    // lane=(c1,g): channel c1, 4-col group g (g<7). 3x b128 per input row.
    {
        int g = lane & 7;
        if (g < 7) {
            const f2* xb = &u.xin[4 * g + 2];               // even idx: 16B aligned
            f2* pout = &pu.p1[c1 * 290 + 3];
            #pragma unroll 1
            for (int k = 0; k < 4; k++) {
                int i = w + 4 * k;                          // pooled row 0..13
                if (i > 13) break;
                f2 o_[2][4];
                #pragma unroll
                for (int dr = 0; dr < 2; dr++)
                    #pragma unroll
                    for (int j = 0; j < 4; j++) o_[dr][j] = sp(bias1);
                #pragma unroll
                for (int q = 0; q < 4; q++) {               // stored row 2i+q
                    f2 rv[6];
                    load_rv6(rv, xb + (2 * i + q) * 32);
                    if (q < 3)  row_fma(o_[0], &wk1[q * 3], rv);        // dr=0, ky=q
                    if (q >= 1) row_fma(o_[1], &wk1[(q - 1) * 3], rv);  // dr=1, ky=q-1
                }
                #pragma unroll
                for (int jj = 0; jj < 2; jj++) {
                    f2 m = PKMAX(PKMAX(o_[0][2 * jj], o_[0][2 * jj + 1]),
                                 PKMAX(o_[1][2 * jj], o_[1][2 * jj + 1]));
                    pout[(i + 1) * 18 + 2 * g + jj] = PKMAX(m, sp(0.f));
                }
            }
        }
    }
    __syncthreads();

    // ---- P3: conv2 + relu + pool -> u.flat (xin dead). wave w owns pooled
    // rows {w, w+4}. lane=(c2,g2). Weights from global w2q (L1), prefetched.
    {
        int c2 = lane >> 2, g2 = lane & 3;
        float bias2 = c2b[c2];
        const float4* wqb = (const float4*)w2q + c2 * 3;    // + ci*48 per ci
        #pragma unroll 1
        for (int k = 0; k < 2; k++) {
            int i = w + 4 * k;                              // pooled row 0..6
            if (i > 6) break;
            f2 acc[2][4];
            #pragma unroll
            for (int dr = 0; dr < 2; dr++)
                #pragma unroll
                for (int j = 0; j < 4; j++) acc[dr][j] = sp(bias2);
            float4 wa = wqb[0], wb = wqb[1], wc = wqb[2];
            #pragma unroll 1
            for (int ci = 0; ci < 8; ci++) {
                float wk[9] = {wa.x, wa.y, wa.z, wa.w, wb.x, wb.y, wb.z, wb.w, wc.x};
                if (ci < 7) {                               // prefetch next ci
                    wa = wqb[(ci + 1) * 48];
                    wb = wqb[(ci + 1) * 48 + 1];
                    wc = wqb[(ci + 1) * 48 + 2];
                }
                // even idx base (16B aligned); g2=3 overruns 2 f2 into the
                // next row's zero halo -> feeds only discarded outputs.
                const f2* pc_ = &pu.p1[ci * 290 + (2 * i) * 18 + 4 * g2 + 2];
                #pragma unroll
                for (int q = 0; q < 4; q++) {               // stored row 2i+q
                    f2 rv[6];
                    load_rv6(rv, pc_ + q * 18);
                    if (q < 3)  row_fma(acc[0], &wk[q * 3], rv);
                    if (q >= 1) row_fma(acc[1], &wk[(q - 1) * 3], rv);
                }
            }
            #pragma unroll
            for (int jj = 0; jj < 2; jj++) {
                int pc = 2 * g2 + jj;
                if (pc < 7) {
                    f2 m = PKMAX(PKMAX(acc[0][2 * jj], acc[0][2 * jj + 1]),
                                 PKMAX(acc[1][2 * jj], acc[1][2 * jj + 1]));
                    u.flat[c2 * 49 + i * 7 + pc] = PKMAX(m, sp(0.f));
                }
            }
        }
    }
    __syncthreads();   // p1 dead from here; pu.fc live

    // ---- P5: fc1 partials. wave owns g-quarter [w*49, w*49+49); weight
    // float4 (global, read once/block) feeds one packed chain for 2 samples.
    {
        const f2* fl = u.flat;
        const float4* wp4 = (const float4*)wT2 + lane;      // + g*64 per k4-group
        int g0 = w * 49;
        f2 a0 = sp(0.f), a1 = sp(0.f);
        #pragma unroll 2
        for (int g = g0; g < g0 + 48; g += 2) {
            float4 wv0 = wp4[(size_t)g * 64];
            float4 wv1 = wp4[(size_t)(g + 1) * 64];
            float4 fA = *(const float4*)&fl[4 * g];
            float4 fB = *(const float4*)&fl[4 * g + 2];
            float4 fC = *(const float4*)&fl[4 * g + 4];
            float4 fD = *(const float4*)&fl[4 * g + 6];
            a0 = PKFMA(sp(wv0.x), mk(fA.x, fA.y), a0);
            a0 = PKFMA(sp(wv0.y), mk(fA.z, fA.w), a0);
            a0 = PKFMA(sp(wv0.z), mk(fB.x, fB.y), a0);
            a0 = PKFMA(sp(wv0.w), mk(fB.z, fB.w), a0);
            a1 = PKFMA(sp(wv1.x), mk(fC.x, fC.y), a1);
            a1 = PKFMA(sp(wv1.y), mk(fC.z, fC.w), a1);
            a1 = PKFMA(sp(wv1.z), mk(fD.x, fD.y), a1);
            a1 = PKFMA(sp(wv1.w), mk(fD.z, fD.w), a1);
        }
        {   // tail group g0+48
            int g = g0 + 48;
            float4 wv = wp4[(size_t)g * 64];
            float4 fA = *(const float4*)&fl[4 * g];
            float4 fB = *(const float4*)&fl[4 * g + 2];
            a0 = PKFMA(sp(wv.x), mk(fA.x, fA.y), a0);
            a0 = PKFMA(sp(wv.y), mk(fA.z, fA.w), a0);
            a0 = PKFMA(sp(wv.z), mk(fB.x, fB.y), a0);
            a0 = PKFMA(sp(wv.w), mk(fB.z, fB.w), a0);
        }
        pu.fc.part[w][lane] = a0 + a1;
    }
    __syncthreads();

    // ---- P6: combine quarters + bias + relu (both samples packed)
    if (t < 64) {
        f2 h = pu.fc.part[0][t] + pu.fc.part[1][t]
             + pu.fc.part[2][t] + pu.fc.part[3][t] + sp(f1b[t]);
        pu.fc.hs[t] = PKMAX(h, sp(0.f));
    }
    __syncthreads();

    // ---- P7: fc2 + feat + sharded BN stats (packed: .x=s0, .y=s1)
    if (t < 4) {
        int j = t;
        f2 a = sp(f2bias[j]);
        #pragma unroll
        for (int o = 0; o < 64; o++) a = PKFMA(sp(f2w[j * 64 + o]), pu.fc.hs[o], a);
        feat[((size_t)blockIdx.x * 2 + 0) * 4 + j] = a.x;
        feat[((size_t)blockIdx.x * 2 + 1) * 4 + j] = a.y;
        int g = blockIdx.x & 63;
        atomicAdd(&stats[g * 8 + j], a.x + a.y);
        atomicAdd(&stats[g * 8 + 4 + j], a.x * a.x + a.y * a.y);
    }
}

// ---------------- BN + encoder + U matvec + PauliZ measure ------------------
// 4 lanes per sample (each does 4 rows of the 16x16 matvec, shfl-reduce).
__global__ __launch_bounds__(128) void quantum_kernel(
    const float* __restrict__ feat, const float* __restrict__ Ug,
    const float* __restrict__ stats, const float* __restrict__ bn_g,
    const float* __restrict__ bn_b, float* __restrict__ out, int B)
{
    __shared__ float2 Us[256];
    __shared__ float sm[8];
    int t = threadIdx.x;                  // 128 threads
    for (int i = t; i < 256; i += 128) Us[i] = ((const float2*)Ug)[i];
    if (t < 8) sm[t] = 0.f;
    __syncthreads();
    {   // parallel gather of 64 shards x 8 (index mod 8 preserved by +128)
        float v = stats[t] + stats[t + 128] + stats[t + 256] + stats[t + 384];
        atomicAdd(&sm[t & 7], v);
    }
    __syncthreads();
    int q = t & 3;                        // row-quad within the sample
    int s = blockIdx.x * 32 + (t >> 2);
    float4 fv = ((const float4*)feat)[s];
    float f[4] = {fv.x, fv.y, fv.z, fv.w};
    float cn[4], sn[4];
    float invB = 1.0f / (float)B;
    #pragma unroll
    for (int w = 0; w < 4; w++) {
        float mean = sm[w] * invB;
        float var  = sm[4 + w] * invB - mean * mean;
        float fh = (f[w] - mean) / sqrtf(var + B_EPS) * bn_g[w] + bn_b[w];
        cn[w] = cosf(0.5f * fh);
        sn[w] = sinf(0.5f * fh);
    }
    // encoded product state: s0_k = prod(c/s) * (-i)^popcount(k)
    float re0[16], im0[16];
    #pragma unroll
    for (int k = 0; k < 16; k++) {
        float mag = ((k & 8) ? sn[0] : cn[0]) * ((k & 4) ? sn[1] : cn[1]) *
                    ((k & 2) ? sn[2] : cn[2]) * ((k & 1) ? sn[3] : cn[3]);
        int m = __popc(k) & 3;
        re0[k] = (m == 0) ? mag : (m == 2) ? -mag : 0.f;
        im0[k] = (m == 1) ? -mag : (m == 3) ? mag : 0.f;
    }
    float o0 = 0.f, o1 = 0.f, o2 = 0.f, o3 = 0.f;
    #pragma unroll
    for (int i = 0; i < 4; i++) {
        int r = q * 4 + i;
        float ar = 0.f, ai = 0.f;
        #pragma unroll
        for (int k = 0; k < 16; k++) {
            float2 uu = Us[r * 16 + k];
            ar += uu.x * re0[k] - uu.y * im0[k];
            ai += uu.x * im0[k] + uu.y * re0[k];
        }
        float p = ar * ar + ai * ai;
        o0 += (r & 8) ? -p : p;
        o1 += (r & 4) ? -p : p;
        o2 += (r & 2) ? -p : p;
        o3 += (r & 1) ? -p : p;
    }
    // reduce across the 4-lane group
    o0 += __shfl_xor(o0, 1);  o0 += __shfl_xor(o0, 2);
    o1 += __shfl_xor(o1, 1);  o1 += __shfl_xor(o1, 2);
    o2 += __shfl_xor(o2, 1);  o2 += __shfl_xor(o2, 2);
    o3 += __shfl_xor(o3, 1);  o3 += __shfl_xor(o3, 2);
    if (q == 0) {
        float4 ov = {o0, o1, o2, o3};
        ((float4*)out)[s] = ov;
    }
}

// ---------------------------------------------------------------------------
extern "C" void kernel_launch(void* const* d_in, const int* in_sizes, int n_in,
                              void* d_out, int out_size, void* d_ws, size_t ws_size,
                              hipStream_t stream)
{
    const float* x   = (const float*)d_in[0];
    const float* c1w = (const float*)d_in[1];
    const float* c1b = (const float*)d_in[2];
    const float* c2w = (const float*)d_in[3];
    const float* c2b = (const float*)d_in[4];
    const float* f1w = (const float*)d_in[5];
    const float* f1b = (const float*)d_in[6];
    const float* f2w = (const float*)d_in[7];
    const float* f2b = (const float*)d_in[8];
    const float* bng = (const float*)d_in[9];
    const float* bnb = (const float*)d_in[10];
    const float* rl  = (const float*)d_in[11];
    float* out = (float*)d_out;

    int B = in_sizes[0] / 784;

    float* wsf   = (float*)d_ws;
    float* feat  = wsf;                          // B*4
    float* wT2   = feat + (size_t)B * 4;         // 784*64 (as [k4][64][4])
    float* U     = wT2 + 784 * 64;               // 512 (float2[256])
    float* stats = U + 512;                      // 512 (64 shards x 8)
    float* w2q   = stats + 512;                  // 1536 ([ci][c2][12], q<9 used)

    prep_kernel<<<197, 256, 0, stream>>>(rl, f1w, c2w, U, wT2, w2q, stats);
    conv_kernel<<<B / 2, 256, 0, stream>>>(x, c1w, c1b, w2q, c2b, wT2,
                                           f1b, f2w, f2b, feat, stats);
    quantum_kernel<<<B / 32, 128, 0, stream>>>(feat, U, stats, bng, bnb, out, B);
}